// Round 16
// baseline (366.813 us; speedup 1.0000x reference)
//
#include <hip/hip_runtime.h>
#include <math.h>

typedef unsigned short u16;
typedef __attribute__((ext_vector_type(8))) short short8;
typedef __attribute__((ext_vector_type(4))) float f32x4;
typedef __attribute__((ext_vector_type(16))) float f32x16;

constexpr int NB = 32, NL = 577, ND = 512, NH = 8, NDK = 64, NFF = 2048;
constexpr int NTOK = NB * NL;          // 18464 tokens
constexpr int NLP  = 640;              // L padded (Q rows and KV rows)
constexpr int LDN  = NL * ND;          // elements per batch (whole-seq LN)
constexpr size_t QKVE = (size_t)NB * NH * NLP * NDK;  // elements per q/k/v tensor
constexpr int NBKT = 32;               // LN2-stat atomic buckets (32 cache lines)

__device__ __forceinline__ u16 f2bf(float f) {
  union { float f; unsigned u; } v; v.f = f;
  unsigned r = v.u + 0x7fffu + ((v.u >> 16) & 1u);   // round-nearest-even
  return (u16)(r >> 16);
}
__device__ __forceinline__ float bf2f(u16 h) {
  union { unsigned u; float f; } v; v.u = ((unsigned)h) << 16; return v.f;
}
__device__ __forceinline__ void gload_lds16(const void* g, void* l) {
  __builtin_amdgcn_global_load_lds((const __attribute__((address_space(1))) void*)g,
                                   (__attribute__((address_space(3))) void*)l, 16, 0, 0);
}
// bijective XCD swizzle (m204): consecutive output ids land on one XCD
__device__ __forceinline__ int xcd_swz(int lin, int nwg) {
  const int xcd = lin & 7, o = lin >> 3;
  const int q = nwg >> 3, r = nwg & 7;
  return (xcd < r ? xcd * (q + 1) : r * (q + 1) + (xcd - r) * q) + o;
}
__device__ __forceinline__ unsigned cvt_pk_bf16(float a, float b) {
  unsigned r;
  asm("v_cvt_pk_bf16_f32 %0, %1, %2" : "=v"(r) : "v"(a), "v"(b));
  return r;
}
__device__ __forceinline__ float exp2_f(float x) {   // raw v_exp_f32 (2^x)
  float r;
  asm("v_exp_f32 %0, %1" : "=v"(r) : "v"(x));
  return r;
}
__device__ __forceinline__ short8 mk8(unsigned a, unsigned b, unsigned c, unsigned d) {
  union { unsigned u[4]; short8 v; } f;
  f.u[0] = a; f.u[1] = b; f.u[2] = c; f.u[3] = d;
  return f.v;
}
__device__ __forceinline__ f32x16 mfma32(short8 a, short8 b, f32x16 c) {
  return __builtin_amdgcn_mfma_f32_32x32x16_bf16(a, b, c, 0, 0, 0);
}
__device__ __forceinline__ f32x4 mfma16(short8 a, short8 b, f32x4 c) {
  return __builtin_amdgcn_mfma_f32_16x16x32_bf16(a, b, c, 0, 0, 0);
}

// ---------------- merged setup: concat bias, q/k/v pad zero, ALL weight --------------
// ---------------- transposes, AND LN1 stats, in ONE launch (disjoint segments) -------
// stats region is zeroed by a stream-ordered hipMemsetAsync BEFORE this launch.
constexpr int SEG0 = 256 * 63 * 64;           // 1032192: pads (+cbias inside)
constexpr int SEG1 = SEG0 + 1536 * 512;       // qkv transpose
constexpr int SEG2 = SEG1 + 512 * 512;        // woT
constexpr int SEG3 = SEG2 + 2048 * 512;       // w1T
constexpr int SEG4 = SEG3 + 2048 * 512;       // w2T
constexpr int SEG5 = SEG4 + 256 * 256;        // LN1 stats (256 blocks: b=blk&31,s=blk>>5)

__global__ void setup_all(u16* __restrict__ qb, u16* __restrict__ kb, u16* __restrict__ vt,
                          float* __restrict__ stats, float* __restrict__ cbias,
                          const float* __restrict__ bq, const float* __restrict__ bk,
                          const float* __restrict__ bv,
                          const float* __restrict__ wq, const float* __restrict__ wk,
                          const float* __restrict__ wv, u16* __restrict__ wqkvT,
                          const float* __restrict__ wo, u16* __restrict__ woT,
                          const float* __restrict__ w1, u16* __restrict__ w1T,
                          const float* __restrict__ w2, u16* __restrict__ w2T,
                          const float* __restrict__ x) {
  __shared__ float s0[4], s1[4];
  const int i = blockIdx.x * 256 + threadIdx.x;
  if (i < 1536) cbias[i] = i < 512 ? bq[i] : (i < 1024 ? bk[i - 512] : bv[i - 1024]);
  if (i < SEG0) {                         // zero pad rows/cols 577..639 of q/k/v
    const int bh = i / (63 * 64), rem = i - bh * (63 * 64);
    const int r = rem >> 6, d = rem & 63;
    const size_t o = ((size_t)bh * NLP + 577 + r) * NDK + d;
    qb[o] = 0; kb[o] = 0;
    const int d2 = rem / 63, kv = rem - d2 * 63;
    vt[((size_t)bh * NDK + d2) * NLP + 577 + kv] = 0;
  } else if (i < SEG1) {                  // wq|wk|wv -> wqkvT[1536][512]
    const int j = i - SEG0;
    const int n = j >> 9, k = j & 511;
    const int s = n >> 9, c = n & 511;
    const float* src = s == 0 ? wq : (s == 1 ? wk : wv);
    wqkvT[j] = f2bf(src[(size_t)k * 512 + c]);
  } else if (i < SEG2) {                  // wo[512][512] -> woT[512][512]
    const int j = i - SEG1;
    const int n = j >> 9, k = j & 511;
    woT[j] = f2bf(wo[(size_t)k * 512 + n]);
  } else if (i < SEG3) {                  // w1[512][2048] -> w1T[2048][512]
    const int j = i - SEG2;
    const int n = j >> 9, k = j & 511;
    w1T[j] = f2bf(w1[(size_t)k * 2048 + n]);
  } else if (i < SEG4) {                  // w2[2048][512] -> w2T[512][2048]
    const int j = i - SEG3;
    const int n = j >> 11, k = j & 2047;
    w2T[j] = f2bf(w2[(size_t)k * 512 + n]);
  } else if (i < SEG5) {                  // LN1 partial stats -> stats[0..63]
    const int blk = (i - SEG4) >> 8;
    const int b = blk & 31, s = blk >> 5;
    const int per4 = LDN / 8 / 4;
    const float4* xb = (const float4*)(x + (size_t)b * LDN + (size_t)s * (LDN / 8));
    float sum = 0.f, ss = 0.f;
    for (int t = threadIdx.x; t < per4; t += 256) {
      float4 v = xb[t];
      sum += v.x + v.y + v.z + v.w;
      ss  += v.x * v.x + v.y * v.y + v.z * v.z + v.w * v.w;
    }
#pragma unroll
    for (int o = 32; o; o >>= 1) { sum += __shfl_down(sum, o); ss += __shfl_down(ss, o); }
    const int lane = threadIdx.x & 63, w = threadIdx.x >> 6;
    if (lane == 0) { s0[w] = sum; s1[w] = ss; }
    __syncthreads();
    if (threadIdx.x == 0) {
      atomicAdd(&stats[b * 2 + 0], s0[0] + s0[1] + s0[2] + s0[3]);
      atomicAdd(&stats[b * 2 + 1], s1[0] + s1[1] + s1[2] + s1[3]);
    }
  }
}

// ---------------- whole-sequence LayerNorm apply ----------------
// f32 input -> bf16 normalized out (LN1; stats flat [64])
__global__ void ln_apply(const float* __restrict__ x, const float* __restrict__ stats,
                         const float* __restrict__ gamma, const float* __restrict__ beta,
                         u16* __restrict__ out) {
  const int nv = LDN / 4;
  const size_t total = (size_t)NB * nv;
  for (size_t i = (size_t)blockIdx.x * blockDim.x + threadIdx.x; i < total;
       i += (size_t)gridDim.x * blockDim.x) {
    const int b = (int)(i / nv);
    const int j = (int)(i - (size_t)b * nv);
    const float sum = stats[b * 2], ssum = stats[b * 2 + 1];
    const float mean = sum / (float)LDN;
    const float var = (ssum - (float)LDN * mean * mean) / (float)(LDN - 1);
    const float inv = 1.0f / (sqrtf(var) + 1e-6f);
    const float4 xv = ((const float4*)x)[i];
    const float4 gv = ((const float4*)gamma)[j];
    const float4 bv = ((const float4*)beta)[j];
    ushort4 o;
    o.x = f2bf(gv.x * ((xv.x - mean) * inv) + bv.x);
    o.y = f2bf(gv.y * ((xv.y - mean) * inv) + bv.y);
    o.z = f2bf(gv.z * ((xv.z - mean) * inv) + bv.z);
    o.w = f2bf(gv.w * ((xv.w - mean) * inv) + bv.w);
    ((ushort4*)out)[i] = o;
  }
}

// bf16 input -> bf16 normalized out (LN2; stats in NBKT buckets, pre-summed per block)
__global__ void ln_apply_b(const u16* __restrict__ x, const float* __restrict__ bkt,
                           const float* __restrict__ gamma, const float* __restrict__ beta,
                           u16* __restrict__ out) {
  __shared__ float sred[64];
  if (threadIdx.x < 64) {
    float s = 0.f;
#pragma unroll
    for (int u = 0; u < NBKT; u++) s += bkt[u * 64 + threadIdx.x];
    sred[threadIdx.x] = s;
  }
  __syncthreads();
  const int nv = LDN / 4;
  const size_t total = (size_t)NB * nv;
  for (size_t i = (size_t)blockIdx.x * blockDim.x + threadIdx.x; i < total;
       i += (size_t)gridDim.x * blockDim.x) {
    const int b = (int)(i / nv);
    const int j = (int)(i - (size_t)b * nv);
    const float sum = sred[b * 2], ssum = sred[b * 2 + 1];
    const float mean = sum / (float)LDN;
    const float var = (ssum - (float)LDN * mean * mean) / (float)(LDN - 1);
    const float inv = 1.0f / (sqrtf(var) + 1e-6f);
    const ushort4 xv = ((const ushort4*)x)[i];
    const float4 gv = ((const float4*)gamma)[j];
    const float4 bv = ((const float4*)beta)[j];
    ushort4 o;
    o.x = f2bf(gv.x * ((bf2f(xv.x) - mean) * inv) + bv.x);
    o.y = f2bf(gv.y * ((bf2f(xv.y) - mean) * inv) + bv.y);
    o.z = f2bf(gv.z * ((bf2f(xv.z) - mean) * inv) + bv.z);
    o.w = f2bf(gv.w * ((bf2f(xv.w) - mean) * inv) + bv.w);
    ((ushort4*)out)[i] = o;
  }
}

// ---------------- 64x128 MFMA GEMM, BK=64, 2-wave blocks, XOR-swizzled LDS ----------
// The universal GEMM: 64-row/2-wave blocks beat 128-row/4-wave at these latency-bound
// shapes (r10 A/B on WO: 93.6 -> 86.5us) -- 2x independent K-loop chains per CU,
// half the threads per barrier. Grid (289, N/128).
// EPI: 0 merged qkv scatter (+bias, q scaled by oscale)
//      4 f32 out = v + bias + bf16res
//      5 bf16 out = gelu(v + bias)
//      6 bf16 out = v + bias + f32res, + NBKT-bucketed LN-stat atomics (r15: the
//        unbucketed version's 9248 same-line atomics serialized ~50us -- G12)
template <int EPI>
__global__ __launch_bounds__(128, 4) void gemm_sm(
    const u16* __restrict__ A, const u16* __restrict__ Bt,
    int M, int N, int K, int lda, int ldb,
    const float* __restrict__ bias,
    const void* __restrict__ res, int ldr,
    void* __restrict__ outp, float* __restrict__ stats, float oscale) {
  __shared__ __align__(16) u16 lA[64 * 64];    // 8 KB
  __shared__ __align__(16) u16 lB[128 * 64];   // 16 KB
  int lin = blockIdx.x + blockIdx.y * gridDim.x;
  lin = xcd_swz(lin, gridDim.x * gridDim.y);
  const int bx = lin / gridDim.y, by = lin - (lin / gridDim.y) * gridDim.y;
  const int m0 = bx * 64, n0 = by * 128;
  const int tid = threadIdx.x, lane = tid & 63, wid = tid >> 6;  // 2 waves
  const int l16 = lane & 15, l4 = lane >> 4;

  f32x4 acc[4][4] = {};

  for (int k0 = 0; k0 < K; k0 += 64) {
#pragma unroll
    for (int j = 0; j < 4; j++) {
      const int cb = j * 128 + wid * 64;
      const int c = cb + lane;
      const int row = c >> 3, g = c & 7;
      gload_lds16(A + (size_t)(m0 + row) * lda + k0 + ((g ^ (row & 7)) << 3), &lA[cb * 8]);
    }
#pragma unroll
    for (int j = 0; j < 8; j++) {
      const int cb = j * 128 + wid * 64;
      const int c = cb + lane;
      const int row = c >> 3, g = c & 7;
      gload_lds16(Bt + (size_t)(n0 + row) * ldb + k0 + ((g ^ (row & 7)) << 3), &lB[cb * 8]);
    }
    __syncthreads();
#pragma unroll
    for (int ks = 0; ks < 2; ks++) {
      short8 af[4], bfr[4];
#pragma unroll
      for (int mi = 0; mi < 4; mi++) {
        const int rl = mi * 16 + l16;
        af[mi] = *(const short8*)&lA[rl * 64 + (((ks * 4 + l4) ^ (rl & 7)) << 3)];
      }
#pragma unroll
      for (int ni = 0; ni < 4; ni++) {
        const int rl = wid * 64 + ni * 16 + l16;
        bfr[ni] = *(const short8*)&lB[rl * 64 + (((ks * 4 + l4) ^ (rl & 7)) << 3)];
      }
#pragma unroll
      for (int mi = 0; mi < 4; mi++)
#pragma unroll
        for (int ni = 0; ni < 4; ni++)
          acc[mi][ni] = mfma16(af[mi], bfr[ni], acc[mi][ni]);
    }
    __syncthreads();
  }

  float sm0 = 0.f, sm1 = 0.f, sq0 = 0.f, sq1 = 0.f;  // EPI6 LN-stat accumulators
#pragma unroll
  for (int mi = 0; mi < 4; mi++) {
#pragma unroll
    for (int r = 0; r < 4; r++) {
      const int row = m0 + mi * 16 + l4 * 4 + r;
      if (row >= M) continue;
      int rb = 0, rl = 0, which = 0;
      if (EPI == 0) { rb = row / NL; rl = row - rb * NL; }
      if (EPI == 6) which = (row >= (m0 / NL + 1) * NL) ? 1 : 0;
#pragma unroll
      for (int ni = 0; ni < 4; ni++) {
        const int col = n0 + wid * 64 + ni * 16 + l16;
        const float v = acc[mi][ni][r];
        if (EPI == 0) {          // merged q/k/v scatter (kind uniform per 64-col span)
          const int kind = col >> 9, c = col & 511, h = c >> 6, d = c & 63;
          const float val = v + bias[col];
          u16* base = (u16*)outp;
          if (kind == 0)
            base[(((size_t)rb * NH + h) * NLP + rl) * NDK + d] = f2bf(val * oscale);
          else if (kind == 1)
            (base + QKVE)[(((size_t)rb * NH + h) * NLP + rl) * NDK + d] = f2bf(val);
          else
            (base + 2 * QKVE)[(((size_t)rb * NH + h) * NDK + d) * NLP + rl] = f2bf(val);
        } else if (EPI == 5) {   // bf16 out = gelu(v + bias), tanh-form via exp
          const float t = v + bias[col];
          const float u = 0.7978845608028654f * t * (1.0f + 0.044715f * t * t);
          const float e = __expf(-2.0f * fabsf(u));
          float th = (1.0f - e) * __builtin_amdgcn_rcpf(1.0f + e);
          th = u < 0.f ? -th : th;
          ((u16*)outp)[(size_t)row * N + col] = f2bf(0.5f * t * (1.0f + th));
        } else if (EPI == 6) {   // bf16 hbuf = v + bias + f32 residual(x); + stats
          const float hv = v + bias[col] + ((const float*)res)[(size_t)row * ldr + col];
          ((u16*)outp)[(size_t)row * N + col] = f2bf(hv);
          if (which) { sm1 += hv; sq1 += hv * hv; }
          else       { sm0 += hv; sq0 += hv * hv; }
        } else {                 // 4: f32 out = v + bias + bf16 residual(hbuf)
          ((float*)outp)[(size_t)row * N + col] =
              v + bias[col] + bf2f(((const u16*)res)[(size_t)row * ldr + col]);
        }
      }
    }
  }
  if (EPI == 6) {
#pragma unroll
    for (int o = 32; o; o >>= 1) {
      sm0 += __shfl_down(sm0, o); sq0 += __shfl_down(sq0, o);
      sm1 += __shfl_down(sm1, o); sq1 += __shfl_down(sq1, o);
    }
    if (lane == 0) {
      float* bkt = stats + (lin & (NBKT - 1)) * 64;   // per-block bucket line
      const int b0 = m0 / NL;
      atomicAdd(&bkt[b0 * 2 + 0], sm0);
      atomicAdd(&bkt[b0 * 2 + 1], sq0);
      if (b0 + 1 < NB) {
        atomicAdd(&bkt[(b0 + 1) * 2 + 0], sm1);
        atomicAdd(&bkt[(b0 + 1) * 2 + 1], sq1);
      }
    }
  }
}

// ---------------- fused flash attention: dual Q-tile, shared-K, in-reg softmax --------
// 1-wave blocks; grid (10 q-pairs, 256 bh). Each wave: TWO adjacent 32-row Q-tiles
// against one K/V stream -> K loads halved per unit work, two independent
// softmax->PV chains give intra-wave MFMA/VALU overlap. Zero LDS.
__global__ __launch_bounds__(64, 2) void attn_fused(
    const u16* __restrict__ qb, const u16* __restrict__ kb,
    const u16* __restrict__ vt, u16* __restrict__ aog) {
  const int lane = threadIdx.x & 63;
  const int l32 = lane & 31, hi = lane >> 5;
  int lin = blockIdx.x + blockIdx.y * gridDim.x;
  lin = xcd_swz(lin, gridDim.x * gridDim.y);
  const int qt = lin % 10, bh = lin / 10;
  const int q0 = qt * 64;
  const u16* QpA = qb + (size_t)bh * NLP * NDK + (size_t)(q0 + l32) * NDK + hi * 8;
  const u16* Kp = kb + (size_t)bh * NLP * NDK + (size_t)l32 * NDK + hi * 8;
  const u16* Vp = vt + (size_t)bh * NDK * NLP + (size_t)l32 * NLP + hi * 8;

  short8 qfA[4], qfB[4];
#pragma unroll
  for (int kc = 0; kc < 4; kc++) {
    qfA[kc] = *(const short8*)(QpA + kc * 16);
    qfB[kc] = *(const short8*)(QpA + (size_t)32 * NDK + kc * 16);
  }

  f32x16 oA0 = {}, oA1 = {}, oB0 = {}, oB1 = {};
  float mA = -3e38f, lA = 0.f, mB = -3e38f, lB = 0.f;

  for (int kv0 = 0; kv0 < NLP; kv0 += 64) {
    // ---- K tile once; QK^T for both Q-tiles (K dies after) ----
    short8 ka[4], kh[4];
#pragma unroll
    for (int kc = 0; kc < 4; kc++) {
      ka[kc] = *(const short8*)(Kp + (size_t)kv0 * NDK + kc * 16);
      kh[kc] = *(const short8*)(Kp + (size_t)(kv0 + 32) * NDK + kc * 16);
    }
    f32x16 sA0 = {}, sA1 = {}, sB0 = {}, sB1 = {};
    __builtin_amdgcn_s_setprio(1);
#pragma unroll
    for (int kc = 0; kc < 4; kc++) {
      sA0 = mfma32(ka[kc], qfA[kc], sA0);
      sA1 = mfma32(kh[kc], qfA[kc], sA1);
      sB0 = mfma32(ka[kc], qfB[kc], sB0);
      sB1 = mfma32(kh[kc], qfB[kc], sB1);
    }
    __builtin_amdgcn_s_setprio(0);
    // ---- V fragments (consumed after softmax) ----
    short8 vf0[4], vf1[4];
#pragma unroll
    for (int ks = 0; ks < 4; ks++) {
      vf0[ks] = *(const short8*)(Vp + (size_t)(kv0 + ks * 16));
      vf1[ks] = *(const short8*)(Vp + (size_t)32 * NLP + (kv0 + ks * 16));
    }
    // ---- tail mask (only last tile has kv >= 577) ----
    if (kv0 + 64 > NL) {
#pragma unroll
      for (int r = 0; r < 16; r++) {
        const int kvb = kv0 + (r & 3) + 8 * (r >> 2) + 4 * hi;
        const bool v0 = kvb < NL, v1 = kvb + 32 < NL;
        sA0[r] = v0 ? sA0[r] : -1e30f;
        sA1[r] = v1 ? sA1[r] : -1e30f;
        sB0[r] = v0 ? sB0[r] : -1e30f;
        sB1[r] = v1 ? sB1[r] : -1e30f;
      }
    }
    // ---- two independent softmax->pack->PV chains (ILP: VALU-A || MFMA-B) ----
#pragma unroll
    for (int half = 0; half < 2; half++) {
      f32x16& s0 = half ? sB0 : sA0;
      f32x16& s1 = half ? sB1 : sA1;
      f32x16& o0 = half ? oB0 : oA0;
      f32x16& o1 = half ? oB1 : oA1;
      float& m = half ? mB : mA;
      float& l = half ? lB : lA;
      float t4[8];
#pragma unroll
      for (int i = 0; i < 8; i++)
        t4[i] = fmaxf(fmaxf(s0[2 * i], s0[2 * i + 1]), fmaxf(s1[2 * i], s1[2 * i + 1]));
      float t = fmaxf(fmaxf(fmaxf(t4[0], t4[1]), fmaxf(t4[2], t4[3])),
                      fmaxf(fmaxf(t4[4], t4[5]), fmaxf(t4[6], t4[7])));
      t = fmaxf(t, __shfl_xor(t, 32));
      if (!__all(t - m <= 8.0f)) {   // defer-max (T13), log2 units: P <= 2^8
        const float mn = fmaxf(m, t);
        const float sc = exp2_f(m - mn);
        m = mn;
        l *= sc;
#pragma unroll
        for (int r = 0; r < 16; r++) { o0[r] *= sc; o1[r] *= sc; }
      }
      float rs = 0.f;
#pragma unroll
      for (int r = 0; r < 16; r++) { s0[r] = exp2_f(s0[r] - m); rs += s0[r]; }
#pragma unroll
      for (int r = 0; r < 16; r++) { s1[r] = exp2_f(s1[r] - m); rs += s1[r]; }
      l += rs + __shfl_xor(rs, 32);

      unsigned w0[8], w1[8], p0[8], p1[8];
#pragma unroll
      for (int i = 0; i < 8; i++) {
        w0[i] = cvt_pk_bf16(s0[2 * i], s0[2 * i + 1]);
        w1[i] = cvt_pk_bf16(s1[2 * i], s1[2 * i + 1]);
      }
#pragma unroll
      for (int i = 0; i < 8; i++) {
        p0[i] = (unsigned)__shfl_xor((int)w0[i], 32);
        p1[i] = (unsigned)__shfl_xor((int)w1[i], 32);
      }
      short8 pa[4];
      pa[0] = mk8(hi ? p0[2] : w0[0], hi ? p0[3] : w0[1], hi ? w0[2] : p0[0], hi ? w0[3] : p0[1]);
      pa[1] = mk8(hi ? p0[6] : w0[4], hi ? p0[7] : w0[5], hi ? w0[6] : p0[4], hi ? w0[7] : p0[5]);
      pa[2] = mk8(hi ? p1[2] : w1[0], hi ? p1[3] : w1[1], hi ? w1[2] : p1[0], hi ? w1[3] : p1[1]);
      pa[3] = mk8(hi ? p1[6] : w1[4], hi ? p1[7] : w1[5], hi ? w1[6] : p1[4], hi ? w1[7] : p1[5]);
      __builtin_amdgcn_s_setprio(1);
#pragma unroll
      for (int ks = 0; ks < 4; ks++) {
        o0 = mfma32(vf0[ks], pa[ks], o0);
        o1 = mfma32(vf1[ks], pa[ks], o1);
      }
      __builtin_amdgcn_s_setprio(0);
    }
  }

  // ---- normalize + store both Q-tiles ----
  const int b = bh >> 3, h = bh & 7;
#pragma unroll
  for (int half = 0; half < 2; half++) {
    const int qg = q0 + half * 32 + l32;
    if (qg >= NL) continue;
    const f32x16& o0 = half ? oB0 : oA0;
    const f32x16& o1 = half ? oB1 : oA1;
    const float inv = 1.0f / (half ? lB : lA);
    u16* orow = aog + ((size_t)b * NL + qg) * ND + h * NDK;
#pragma unroll
    for (int r = 0; r < 16; r += 2) {
      const int d = (r & 3) + 4 * hi + 8 * (r >> 2);
      *(unsigned*)(orow + d) = cvt_pk_bf16(o0[r] * inv, o0[r + 1] * inv);
      *(unsigned*)(orow + 32 + d) = cvt_pk_bf16(o1[r] * inv, o1[r + 1] * inv);
    }
  }
}

extern "C" void kernel_launch(void* const* d_in, const int* in_sizes, int n_in,
                              void* d_out, int out_size, void* d_ws, size_t ws_size,
                              hipStream_t stream) {
  const float* x      = (const float*)d_in[0];
  const float* gamma1 = (const float*)d_in[1];
  const float* beta1  = (const float*)d_in[2];
  const float* gamma2 = (const float*)d_in[3];
  const float* beta2  = (const float*)d_in[4];
  const float* wq = (const float*)d_in[5];
  const float* bq = (const float*)d_in[6];
  const float* wk = (const float*)d_in[7];
  const float* bk = (const float*)d_in[8];
  const float* wv = (const float*)d_in[9];
  const float* bv = (const float*)d_in[10];
  const float* wo = (const float*)d_in[11];
  const float* bo = (const float*)d_in[12];
  const float* w1 = (const float*)d_in[13];
  const float* b1 = (const float*)d_in[14];
  const float* w2 = (const float*)d_in[15];
  const float* b2 = (const float*)d_in[16];
  float* out = (float*)d_out;

  char* ws = (char*)d_ws;
  size_t off = 0;
  auto take = [&](size_t bytes) { size_t o = off; off += (bytes + 255) & ~(size_t)255; return o; };
  const size_t SLK = 2u << 20;  // tail slack: edge tiles may over-read

  // stats layout: [0..63] = LN1 flat (setup_all atomics; pre-zeroed by memset),
  // [64 .. 64+NBKT*64) = LN2 buckets (gemm_sm<6> bucketed atomics).
  const size_t STATS_B = (64 + NBKT * 64) * 4;
  float* stats = (float*)(ws + take(STATS_B));
  float* stats1 = stats;
  float* stats2 = stats + 64;        // bucket base
  float* cbias = (float*)(ws + take(1536 * 4));
  u16* wqkvT = (u16*)(ws + take((size_t)1536 * 512 * 2));
  u16* woT = (u16*)(ws + take((size_t)512 * 512 * 2));
  u16* w1T = (u16*)(ws + take((size_t)512 * 2048 * 2));
  u16* w2T = (u16*)(ws + take((size_t)2048 * 512 * 2));
  u16* hbuf = (u16*)(ws + take((size_t)NTOK * ND * 2 + SLK));   // h = attn+x, bf16
  u16* qb = (u16*)(ws + take(3 * QKVE * 2 + SLK));
  u16* kb = qb + QKVE;
  u16* vt = kb + QKVE;
  u16* aog = (u16*)(ws + take((size_t)NTOK * ND * 2 + SLK));  // attn out, later ln2 out
  size_t r7 = take((size_t)NTOK * NFF * 2 + SLK);
  u16* xn   = (u16*)(ws + r7);
  u16* ubuf = (u16*)(ws + r7);

  // zero stats FIRST (stream-ordered before any stat atomics)
  hipMemsetAsync(stats, 0, STATS_B, stream);

  // merged setup: concat bias + q/k/v pads + ALL weight transposes + LN1 stats
  setup_all<<<SEG5 / 256, 256, 0, stream>>>(qb, kb, vt, stats, cbias,
                                            bq, bk, bv, wq, wk, wv, wqkvT,
                                            wo, woT, w1, w1T, w2, w2T, x);

  // LN1 apply -> xn (bf16)
  ln_apply<<<2048, 256, 0, stream>>>(x, stats1, gamma1, beta1, xn);

  // merged Q,K,V projection (q scaled by 1/sqrt(512)*log2e for exp2-domain softmax)
  constexpr float QSCALE = 0.04419417382415922f * 1.4426950408889634f;
  gemm_sm<0><<<dim3(289, 12), 128, 0, stream>>>(xn, wqkvT, NTOK, 1536, ND, ND, ND,
                                                cbias, nullptr, 0, qb, nullptr, QSCALE);

  // fused flash attention -> aog
  attn_fused<<<dim3(10, NB * NH), 64, 0, stream>>>(qb, kb, vt, aog);

  // output projection + residual(x) -> hbuf (bf16), bucketed LN2 stats
  gemm_sm<6><<<dim3(289, 4), 128, 0, stream>>>(aog, woT, NTOK, ND, ND, ND, ND,
                                               bo, x, ND, hbuf, stats2, 1.0f);

  // LN2 apply -> g (bf16, reuses aog); sums the NBKT buckets in-kernel
  ln_apply_b<<<2048, 256, 0, stream>>>(hbuf, stats2, gamma2, beta2, aog);

  // FFN
  gemm_sm<5><<<dim3(289, 16), 128, 0, stream>>>(aog, w1T, NTOK, NFF, ND, ND, ND,
                                                b1, nullptr, 0, ubuf, nullptr, 1.0f);
  gemm_sm<4><<<dim3(289, 4), 128, 0, stream>>>(ubuf, w2T, NTOK, ND, NFF, NFF, NFF,
                                               b2, hbuf, ND, out, nullptr, 1.0f);
}

// Round 17
// 363.844 us; speedup vs baseline: 1.0082x; 1.0082x over previous
//
#include <hip/hip_runtime.h>
#include <math.h>

typedef unsigned short u16;
typedef __attribute__((ext_vector_type(8))) short short8;
typedef __attribute__((ext_vector_type(4))) float f32x4;
typedef __attribute__((ext_vector_type(16))) float f32x16;

constexpr int NB = 32, NL = 577, ND = 512, NH = 8, NDK = 64, NFF = 2048;
constexpr int NTOK = NB * NL;          // 18464 tokens
constexpr int NLP  = 640;              // L padded (Q rows and KV rows)
constexpr int LDN  = NL * ND;          // elements per batch (whole-seq LN)
constexpr size_t QKVE = (size_t)NB * NH * NLP * NDK;  // elements per q/k/v tensor
constexpr int NBKT = 32;               // LN2-stat atomic buckets (32 cache lines)

__device__ __forceinline__ u16 f2bf(float f) {
  union { float f; unsigned u; } v; v.f = f;
  unsigned r = v.u + 0x7fffu + ((v.u >> 16) & 1u);   // round-nearest-even
  return (u16)(r >> 16);
}
__device__ __forceinline__ float bf2f(u16 h) {
  union { unsigned u; float f; } v; v.u = ((unsigned)h) << 16; return v.f;
}
__device__ __forceinline__ void gload_lds16(const void* g, void* l) {
  __builtin_amdgcn_global_load_lds((const __attribute__((address_space(1))) void*)g,
                                   (__attribute__((address_space(3))) void*)l, 16, 0, 0);
}
// bijective XCD swizzle (m204): consecutive output ids land on one XCD
__device__ __forceinline__ int xcd_swz(int lin, int nwg) {
  const int xcd = lin & 7, o = lin >> 3;
  const int q = nwg >> 3, r = nwg & 7;
  return (xcd < r ? xcd * (q + 1) : r * (q + 1) + (xcd - r) * q) + o;
}
__device__ __forceinline__ unsigned cvt_pk_bf16(float a, float b) {
  unsigned r;
  asm("v_cvt_pk_bf16_f32 %0, %1, %2" : "=v"(r) : "v"(a), "v"(b));
  return r;
}
__device__ __forceinline__ float exp2_f(float x) {   // raw v_exp_f32 (2^x)
  float r;
  asm("v_exp_f32 %0, %1" : "=v"(r) : "v"(x));
  return r;
}
__device__ __forceinline__ short8 mk8(unsigned a, unsigned b, unsigned c, unsigned d) {
  union { unsigned u[4]; short8 v; } f;
  f.u[0] = a; f.u[1] = b; f.u[2] = c; f.u[3] = d;
  return f.v;
}
__device__ __forceinline__ f32x16 mfma32(short8 a, short8 b, f32x16 c) {
  return __builtin_amdgcn_mfma_f32_32x32x16_bf16(a, b, c, 0, 0, 0);
}
__device__ __forceinline__ f32x4 mfma16(short8 a, short8 b, f32x4 c) {
  return __builtin_amdgcn_mfma_f32_16x16x32_bf16(a, b, c, 0, 0, 0);
}

// ---------------- merged setup: concat bias, q/k/v pad zero, ALL weight --------------
// ---------------- transposes, AND LN1 stats, in ONE launch (disjoint segments) -------
// stats region is zeroed by a stream-ordered hipMemsetAsync BEFORE this launch.
constexpr int SEG0 = 256 * 63 * 64;           // 1032192: pads (+cbias inside)
constexpr int SEG1 = SEG0 + 1536 * 512;       // qkv transpose
constexpr int SEG2 = SEG1 + 512 * 512;        // woT
constexpr int SEG3 = SEG2 + 2048 * 512;       // w1T
constexpr int SEG4 = SEG3 + 2048 * 512;       // w2T
constexpr int SEG5 = SEG4 + 256 * 256;        // LN1 stats (256 blocks: b=blk&31,s=blk>>5)

__global__ void setup_all(u16* __restrict__ qb, u16* __restrict__ kb, u16* __restrict__ vt,
                          float* __restrict__ stats, float* __restrict__ cbias,
                          const float* __restrict__ bq, const float* __restrict__ bk,
                          const float* __restrict__ bv,
                          const float* __restrict__ wq, const float* __restrict__ wk,
                          const float* __restrict__ wv, u16* __restrict__ wqkvT,
                          const float* __restrict__ wo, u16* __restrict__ woT,
                          const float* __restrict__ w1, u16* __restrict__ w1T,
                          const float* __restrict__ w2, u16* __restrict__ w2T,
                          const float* __restrict__ x) {
  __shared__ float s0[4], s1[4];
  const int i = blockIdx.x * 256 + threadIdx.x;
  if (i < 1536) cbias[i] = i < 512 ? bq[i] : (i < 1024 ? bk[i - 512] : bv[i - 1024]);
  if (i < SEG0) {                         // zero pad rows/cols 577..639 of q/k/v
    const int bh = i / (63 * 64), rem = i - bh * (63 * 64);
    const int r = rem >> 6, d = rem & 63;
    const size_t o = ((size_t)bh * NLP + 577 + r) * NDK + d;
    qb[o] = 0; kb[o] = 0;
    const int d2 = rem / 63, kv = rem - d2 * 63;
    vt[((size_t)bh * NDK + d2) * NLP + 577 + kv] = 0;
  } else if (i < SEG1) {                  // wq|wk|wv -> wqkvT[1536][512]
    const int j = i - SEG0;
    const int n = j >> 9, k = j & 511;
    const int s = n >> 9, c = n & 511;
    const float* src = s == 0 ? wq : (s == 1 ? wk : wv);
    wqkvT[j] = f2bf(src[(size_t)k * 512 + c]);
  } else if (i < SEG2) {                  // wo[512][512] -> woT[512][512]
    const int j = i - SEG1;
    const int n = j >> 9, k = j & 511;
    woT[j] = f2bf(wo[(size_t)k * 512 + n]);
  } else if (i < SEG3) {                  // w1[512][2048] -> w1T[2048][512]
    const int j = i - SEG2;
    const int n = j >> 9, k = j & 511;
    w1T[j] = f2bf(w1[(size_t)k * 2048 + n]);
  } else if (i < SEG4) {                  // w2[2048][512] -> w2T[512][2048]
    const int j = i - SEG3;
    const int n = j >> 11, k = j & 2047;
    w2T[j] = f2bf(w2[(size_t)k * 512 + n]);
  } else if (i < SEG5) {                  // LN1 partial stats -> stats[0..63]
    const int blk = (i - SEG4) >> 8;
    const int b = blk & 31, s = blk >> 5;
    const int per4 = LDN / 8 / 4;
    const float4* xb = (const float4*)(x + (size_t)b * LDN + (size_t)s * (LDN / 8));
    float sum = 0.f, ss = 0.f;
    for (int t = threadIdx.x; t < per4; t += 256) {
      float4 v = xb[t];
      sum += v.x + v.y + v.z + v.w;
      ss  += v.x * v.x + v.y * v.y + v.z * v.z + v.w * v.w;
    }
#pragma unroll
    for (int o = 32; o; o >>= 1) { sum += __shfl_down(sum, o); ss += __shfl_down(ss, o); }
    const int lane = threadIdx.x & 63, w = threadIdx.x >> 6;
    if (lane == 0) { s0[w] = sum; s1[w] = ss; }
    __syncthreads();
    if (threadIdx.x == 0) {
      atomicAdd(&stats[b * 2 + 0], s0[0] + s0[1] + s0[2] + s0[3]);
      atomicAdd(&stats[b * 2 + 1], s1[0] + s1[1] + s1[2] + s1[3]);
    }
  }
}

// ---------------- whole-sequence LayerNorm apply ----------------
// f32 input -> bf16 normalized out (LN1; stats flat [64])
__global__ void ln_apply(const float* __restrict__ x, const float* __restrict__ stats,
                         const float* __restrict__ gamma, const float* __restrict__ beta,
                         u16* __restrict__ out) {
  const int nv = LDN / 4;
  const size_t total = (size_t)NB * nv;
  for (size_t i = (size_t)blockIdx.x * blockDim.x + threadIdx.x; i < total;
       i += (size_t)gridDim.x * blockDim.x) {
    const int b = (int)(i / nv);
    const int j = (int)(i - (size_t)b * nv);
    const float sum = stats[b * 2], ssum = stats[b * 2 + 1];
    const float mean = sum / (float)LDN;
    const float var = (ssum - (float)LDN * mean * mean) / (float)(LDN - 1);
    const float inv = 1.0f / (sqrtf(var) + 1e-6f);
    const float4 xv = ((const float4*)x)[i];
    const float4 gv = ((const float4*)gamma)[j];
    const float4 bv = ((const float4*)beta)[j];
    ushort4 o;
    o.x = f2bf(gv.x * ((xv.x - mean) * inv) + bv.x);
    o.y = f2bf(gv.y * ((xv.y - mean) * inv) + bv.y);
    o.z = f2bf(gv.z * ((xv.z - mean) * inv) + bv.z);
    o.w = f2bf(gv.w * ((xv.w - mean) * inv) + bv.w);
    ((ushort4*)out)[i] = o;
  }
}

// bf16 input -> bf16 normalized out (LN2; stats in NBKT buckets, pre-summed per block)
__global__ void ln_apply_b(const u16* __restrict__ x, const float* __restrict__ bkt,
                           const float* __restrict__ gamma, const float* __restrict__ beta,
                           u16* __restrict__ out) {
  __shared__ float sred[64];
  if (threadIdx.x < 64) {
    float s = 0.f;
#pragma unroll
    for (int u = 0; u < NBKT; u++) s += bkt[u * 64 + threadIdx.x];
    sred[threadIdx.x] = s;
  }
  __syncthreads();
  const int nv = LDN / 4;
  const size_t total = (size_t)NB * nv;
  for (size_t i = (size_t)blockIdx.x * blockDim.x + threadIdx.x; i < total;
       i += (size_t)gridDim.x * blockDim.x) {
    const int b = (int)(i / nv);
    const int j = (int)(i - (size_t)b * nv);
    const float sum = sred[b * 2], ssum = sred[b * 2 + 1];
    const float mean = sum / (float)LDN;
    const float var = (ssum - (float)LDN * mean * mean) / (float)(LDN - 1);
    const float inv = 1.0f / (sqrtf(var) + 1e-6f);
    const ushort4 xv = ((const ushort4*)x)[i];
    const float4 gv = ((const float4*)gamma)[j];
    const float4 bv = ((const float4*)beta)[j];
    ushort4 o;
    o.x = f2bf(gv.x * ((bf2f(xv.x) - mean) * inv) + bv.x);
    o.y = f2bf(gv.y * ((bf2f(xv.y) - mean) * inv) + bv.y);
    o.z = f2bf(gv.z * ((bf2f(xv.z) - mean) * inv) + bv.z);
    o.w = f2bf(gv.w * ((bf2f(xv.w) - mean) * inv) + bv.w);
    ((ushort4*)out)[i] = o;
  }
}

// ---------------- 128x128 MFMA GEMM, BK=64, XOR-swizzled LDS (single-buffer) ----------
// For the wide-N GEMMs QKV (N=1536) and FFN1 (N=2048): 128-row tiles amortize B-panel
// fetch (r16: 64-row tiles raised FETCH 22.7->25.7MB and dur 86->92us on FFN1).
// launch_bounds(256,4): VGPR 60, 4 blocks/CU (measured-best; (256,5) regressed).
// EPI: 0 merged qkv scatter (+bias, q scaled)  5 bf16 gelu(v+bias)
template <int EPI>
__global__ __launch_bounds__(256, 4) void gemm_bt(
    const u16* __restrict__ A, const u16* __restrict__ Bt,
    int M, int N, int K, int lda, int ldb,
    const float* __restrict__ bias,
    void* __restrict__ outp, float oscale) {
  __shared__ __align__(16) u16 lA[128 * 64];
  __shared__ __align__(16) u16 lB[128 * 64];
  int lin = blockIdx.x + blockIdx.y * gridDim.x;
  lin = xcd_swz(lin, gridDim.x * gridDim.y);
  const int bx = lin / gridDim.y, by = lin - (lin / gridDim.y) * gridDim.y;
  const int m0 = bx * 128, n0 = by * 128;
  const int tid = threadIdx.x, lane = tid & 63, wid = tid >> 6;
  const int l16 = lane & 15, l4 = lane >> 4;
  const int wm = wid >> 1, wn = wid & 1;

  f32x4 acc[4][4] = {};

  for (int k0 = 0; k0 < K; k0 += 64) {
#pragma unroll
    for (int j = 0; j < 4; j++) {
      const int cb = j * 256 + wid * 64;   // wave-uniform 16B-chunk base
      const int c = cb + lane;
      const int row = c >> 3, g = c & 7;   // 8 granules of 8 u16 per row
      const int scol = k0 + ((g ^ (row & 7)) << 3);  // pre-swizzled source granule
      gload_lds16(A + (size_t)(m0 + row) * lda + scol, &lA[cb * 8]);
      gload_lds16(Bt + (size_t)(n0 + row) * ldb + scol, &lB[cb * 8]);
    }
    __syncthreads();
#pragma unroll
    for (int ks = 0; ks < 2; ks++) {
      short8 af[4], bfr[4];
#pragma unroll
      for (int mi = 0; mi < 4; mi++) {
        const int rl = wm * 64 + mi * 16 + l16;
        af[mi] = *(const short8*)&lA[rl * 64 + (((ks * 4 + l4) ^ (rl & 7)) << 3)];
      }
#pragma unroll
      for (int ni = 0; ni < 4; ni++) {
        const int rl = wn * 64 + ni * 16 + l16;
        bfr[ni] = *(const short8*)&lB[rl * 64 + (((ks * 4 + l4) ^ (rl & 7)) << 3)];
      }
#pragma unroll
      for (int mi = 0; mi < 4; mi++)
#pragma unroll
        for (int ni = 0; ni < 4; ni++)
          acc[mi][ni] = mfma16(af[mi], bfr[ni], acc[mi][ni]);
    }
    __syncthreads();
  }

#pragma unroll
  for (int mi = 0; mi < 4; mi++) {
#pragma unroll
    for (int r = 0; r < 4; r++) {
      const int row = m0 + wm * 64 + mi * 16 + l4 * 4 + r;
      if (row >= M) continue;
      int rb = 0, rl = 0;
      if (EPI == 0) { rb = row / NL; rl = row - rb * NL; }
#pragma unroll
      for (int ni = 0; ni < 4; ni++) {
        const int col = n0 + wn * 64 + ni * 16 + l16;
        if (col >= N) continue;
        const float v = acc[mi][ni][r];
        if (EPI == 0) {          // merged q/k/v scatter
          const int kind = col >> 9, c = col & 511, h = c >> 6, d = c & 63;
          const float val = v + bias[col];
          u16* base = (u16*)outp;
          if (kind == 0)
            base[(((size_t)rb * NH + h) * NLP + rl) * NDK + d] = f2bf(val * oscale);
          else if (kind == 1)
            (base + QKVE)[(((size_t)rb * NH + h) * NLP + rl) * NDK + d] = f2bf(val);
          else
            (base + 2 * QKVE)[(((size_t)rb * NH + h) * NDK + d) * NLP + rl] = f2bf(val);
        } else {                 // 5: bf16 out = gelu(v + bias), tanh-form via exp
          const float t = v + bias[col];
          const float u = 0.7978845608028654f * t * (1.0f + 0.044715f * t * t);
          const float e = __expf(-2.0f * fabsf(u));
          float th = (1.0f - e) * __builtin_amdgcn_rcpf(1.0f + e);
          th = u < 0.f ? -th : th;
          ((u16*)outp)[(size_t)row * N + col] = f2bf(0.5f * t * (1.0f + th));
        }
      }
    }
  }
}

// ---------------- 64x128 MFMA GEMM, BK=64, 2-wave blocks (small-N latency shape) -----
// For WO / FFN2 (N=512): grid (289,4) = 1156 blocks (best measured WO structure).
// EPI: 4 f32 out = v + bias + bf16res
//      6 bf16 out = v+bias+f32res, + NBKT-bucketed LN-stat atomics (r15: the
//        unbucketed version's 9248 same-line atomics serialized ~50us -- G12)
template <int EPI>
__global__ __launch_bounds__(128, 4) void gemm_sm(
    const u16* __restrict__ A, const u16* __restrict__ Bt,
    int M, int N, int K, int lda, int ldb,
    const float* __restrict__ bias,
    const void* __restrict__ res, int ldr,
    void* __restrict__ outp, float* __restrict__ stats) {
  __shared__ __align__(16) u16 lA[64 * 64];    // 8 KB
  __shared__ __align__(16) u16 lB[128 * 64];   // 16 KB
  int lin = blockIdx.x + blockIdx.y * gridDim.x;
  lin = xcd_swz(lin, gridDim.x * gridDim.y);
  const int bx = lin / gridDim.y, by = lin - (lin / gridDim.y) * gridDim.y;
  const int m0 = bx * 64, n0 = by * 128;
  const int tid = threadIdx.x, lane = tid & 63, wid = tid >> 6;  // 2 waves
  const int l16 = lane & 15, l4 = lane >> 4;

  f32x4 acc[4][4] = {};

  for (int k0 = 0; k0 < K; k0 += 64) {
#pragma unroll
    for (int j = 0; j < 4; j++) {
      const int cb = j * 128 + wid * 64;
      const int c = cb + lane;
      const int row = c >> 3, g = c & 7;
      gload_lds16(A + (size_t)(m0 + row) * lda + k0 + ((g ^ (row & 7)) << 3), &lA[cb * 8]);
    }
#pragma unroll
    for (int j = 0; j < 8; j++) {
      const int cb = j * 128 + wid * 64;
      const int c = cb + lane;
      const int row = c >> 3, g = c & 7;
      gload_lds16(Bt + (size_t)(n0 + row) * ldb + k0 + ((g ^ (row & 7)) << 3), &lB[cb * 8]);
    }
    __syncthreads();
#pragma unroll
    for (int ks = 0; ks < 2; ks++) {
      short8 af[4], bfr[4];
#pragma unroll
      for (int mi = 0; mi < 4; mi++) {
        const int rl = mi * 16 + l16;
        af[mi] = *(const short8*)&lA[rl * 64 + (((ks * 4 + l4) ^ (rl & 7)) << 3)];
      }
#pragma unroll
      for (int ni = 0; ni < 4; ni++) {
        const int rl = wid * 64 + ni * 16 + l16;
        bfr[ni] = *(const short8*)&lB[rl * 64 + (((ks * 4 + l4) ^ (rl & 7)) << 3)];
      }
#pragma unroll
      for (int mi = 0; mi < 4; mi++)
#pragma unroll
        for (int ni = 0; ni < 4; ni++)
          acc[mi][ni] = mfma16(af[mi], bfr[ni], acc[mi][ni]);
    }
    __syncthreads();
  }

  float sm0 = 0.f, sm1 = 0.f, sq0 = 0.f, sq1 = 0.f;  // EPI6 LN-stat accumulators
#pragma unroll
  for (int mi = 0; mi < 4; mi++) {
#pragma unroll
    for (int r = 0; r < 4; r++) {
      const int row = m0 + mi * 16 + l4 * 4 + r;
      if (row >= M) continue;
      int which = 0;
      if (EPI == 6) which = (row >= (m0 / NL + 1) * NL) ? 1 : 0;
#pragma unroll
      for (int ni = 0; ni < 4; ni++) {
        const int col = n0 + wid * 64 + ni * 16 + l16;
        const float v = acc[mi][ni][r];
        if (EPI == 6) {          // bf16 hbuf = v + bias + f32 residual(x); + stats
          const float hv = v + bias[col] + ((const float*)res)[(size_t)row * ldr + col];
          ((u16*)outp)[(size_t)row * N + col] = f2bf(hv);
          if (which) { sm1 += hv; sq1 += hv * hv; }
          else       { sm0 += hv; sq0 += hv * hv; }
        } else {                 // 4: f32 out = v + bias + bf16 residual(hbuf)
          ((float*)outp)[(size_t)row * N + col] =
              v + bias[col] + bf2f(((const u16*)res)[(size_t)row * ldr + col]);
        }
      }
    }
  }
  if (EPI == 6) {
#pragma unroll
    for (int o = 32; o; o >>= 1) {
      sm0 += __shfl_down(sm0, o); sq0 += __shfl_down(sq0, o);
      sm1 += __shfl_down(sm1, o); sq1 += __shfl_down(sq1, o);
    }
    if (lane == 0) {
      float* bkt = stats + (lin & (NBKT - 1)) * 64;   // per-block bucket line
      const int b0 = m0 / NL;
      atomicAdd(&bkt[b0 * 2 + 0], sm0);
      atomicAdd(&bkt[b0 * 2 + 1], sq0);
      if (b0 + 1 < NB) {
        atomicAdd(&bkt[(b0 + 1) * 2 + 0], sm1);
        atomicAdd(&bkt[(b0 + 1) * 2 + 1], sq1);
      }
    }
  }
}

// ---------------- fused flash attention: dual Q-tile, shared-K, in-reg softmax --------
// 1-wave blocks; grid (10 q-pairs, 256 bh). Each wave: TWO adjacent 32-row Q-tiles
// against one K/V stream -> K loads halved per unit work, two independent
// softmax->PV chains give intra-wave MFMA/VALU overlap. Zero LDS.
__global__ __launch_bounds__(64, 2) void attn_fused(
    const u16* __restrict__ qb, const u16* __restrict__ kb,
    const u16* __restrict__ vt, u16* __restrict__ aog) {
  const int lane = threadIdx.x & 63;
  const int l32 = lane & 31, hi = lane >> 5;
  int lin = blockIdx.x + blockIdx.y * gridDim.x;
  lin = xcd_swz(lin, gridDim.x * gridDim.y);
  const int qt = lin % 10, bh = lin / 10;
  const int q0 = qt * 64;
  const u16* QpA = qb + (size_t)bh * NLP * NDK + (size_t)(q0 + l32) * NDK + hi * 8;
  const u16* Kp = kb + (size_t)bh * NLP * NDK + (size_t)l32 * NDK + hi * 8;
  const u16* Vp = vt + (size_t)bh * NDK * NLP + (size_t)l32 * NLP + hi * 8;

  short8 qfA[4], qfB[4];
#pragma unroll
  for (int kc = 0; kc < 4; kc++) {
    qfA[kc] = *(const short8*)(QpA + kc * 16);
    qfB[kc] = *(const short8*)(QpA + (size_t)32 * NDK + kc * 16);
  }

  f32x16 oA0 = {}, oA1 = {}, oB0 = {}, oB1 = {};
  float mA = -3e38f, lA = 0.f, mB = -3e38f, lB = 0.f;

  for (int kv0 = 0; kv0 < NLP; kv0 += 64) {
    // ---- K tile once; QK^T for both Q-tiles (K dies after) ----
    short8 ka[4], kh[4];
#pragma unroll
    for (int kc = 0; kc < 4; kc++) {
      ka[kc] = *(const short8*)(Kp + (size_t)kv0 * NDK + kc * 16);
      kh[kc] = *(const short8*)(Kp + (size_t)(kv0 + 32) * NDK + kc * 16);
    }
    f32x16 sA0 = {}, sA1 = {}, sB0 = {}, sB1 = {};
    __builtin_amdgcn_s_setprio(1);
#pragma unroll
    for (int kc = 0; kc < 4; kc++) {
      sA0 = mfma32(ka[kc], qfA[kc], sA0);
      sA1 = mfma32(kh[kc], qfA[kc], sA1);
      sB0 = mfma32(ka[kc], qfB[kc], sB0);
      sB1 = mfma32(kh[kc], qfB[kc], sB1);
    }
    __builtin_amdgcn_s_setprio(0);
    // ---- V fragments (consumed after softmax) ----
    short8 vf0[4], vf1[4];
#pragma unroll
    for (int ks = 0; ks < 4; ks++) {
      vf0[ks] = *(const short8*)(Vp + (size_t)(kv0 + ks * 16));
      vf1[ks] = *(const short8*)(Vp + (size_t)32 * NLP + (kv0 + ks * 16));
    }
    // ---- tail mask (only last tile has kv >= 577) ----
    if (kv0 + 64 > NL) {
#pragma unroll
      for (int r = 0; r < 16; r++) {
        const int kvb = kv0 + (r & 3) + 8 * (r >> 2) + 4 * hi;
        const bool v0 = kvb < NL, v1 = kvb + 32 < NL;
        sA0[r] = v0 ? sA0[r] : -1e30f;
        sA1[r] = v1 ? sA1[r] : -1e30f;
        sB0[r] = v0 ? sB0[r] : -1e30f;
        sB1[r] = v1 ? sB1[r] : -1e30f;
      }
    }
    // ---- two independent softmax->pack->PV chains (ILP: VALU-A || MFMA-B) ----
#pragma unroll
    for (int half = 0; half < 2; half++) {
      f32x16& s0 = half ? sB0 : sA0;
      f32x16& s1 = half ? sB1 : sA1;
      f32x16& o0 = half ? oB0 : oA0;
      f32x16& o1 = half ? oB1 : oA1;
      float& m = half ? mB : mA;
      float& l = half ? lB : lA;
      float t4[8];
#pragma unroll
      for (int i = 0; i < 8; i++)
        t4[i] = fmaxf(fmaxf(s0[2 * i], s0[2 * i + 1]), fmaxf(s1[2 * i], s1[2 * i + 1]));
      float t = fmaxf(fmaxf(fmaxf(t4[0], t4[1]), fmaxf(t4[2], t4[3])),
                      fmaxf(fmaxf(t4[4], t4[5]), fmaxf(t4[6], t4[7])));
      t = fmaxf(t, __shfl_xor(t, 32));
      if (!__all(t - m <= 8.0f)) {   // defer-max (T13), log2 units: P <= 2^8
        const float mn = fmaxf(m, t);
        const float sc = exp2_f(m - mn);
        m = mn;
        l *= sc;
#pragma unroll
        for (int r = 0; r < 16; r++) { o0[r] *= sc; o1[r] *= sc; }
      }
      float rs = 0.f;
#pragma unroll
      for (int r = 0; r < 16; r++) { s0[r] = exp2_f(s0[r] - m); rs += s0[r]; }
#pragma unroll
      for (int r = 0; r < 16; r++) { s1[r] = exp2_f(s1[r] - m); rs += s1[r]; }
      l += rs + __shfl_xor(rs, 32);

      unsigned w0[8], w1[8], p0[8], p1[8];
#pragma unroll
      for (int i = 0; i < 8; i++) {
        w0[i] = cvt_pk_bf16(s0[2 * i], s0[2 * i + 1]);
        w1[i] = cvt_pk_bf16(s1[2 * i], s1[2 * i + 1]);
      }
#pragma unroll
      for (int i = 0; i < 8; i++) {
        p0[i] = (unsigned)__shfl_xor((int)w0[i], 32);
        p1[i] = (unsigned)__shfl_xor((int)w1[i], 32);
      }
      short8 pa[4];
      pa[0] = mk8(hi ? p0[2] : w0[0], hi ? p0[3] : w0[1], hi ? w0[2] : p0[0], hi ? w0[3] : p0[1]);
      pa[1] = mk8(hi ? p0[6] : w0[4], hi ? p0[7] : w0[5], hi ? w0[6] : p0[4], hi ? w0[7] : p0[5]);
      pa[2] = mk8(hi ? p1[2] : w1[0], hi ? p1[3] : w1[1], hi ? w1[2] : p1[0], hi ? w1[3] : p1[1]);
      pa[3] = mk8(hi ? p1[6] : w1[4], hi ? p1[7] : w1[5], hi ? w1[6] : p1[4], hi ? w1[7] : p1[5]);
      __builtin_amdgcn_s_setprio(1);
#pragma unroll
      for (int ks = 0; ks < 4; ks++) {
        o0 = mfma32(vf0[ks], pa[ks], o0);
        o1 = mfma32(vf1[ks], pa[ks], o1);
      }
      __builtin_amdgcn_s_setprio(0);
    }
  }

  // ---- normalize + store both Q-tiles ----
  const int b = bh >> 3, h = bh & 7;
#pragma unroll
  for (int half = 0; half < 2; half++) {
    const int qg = q0 + half * 32 + l32;
    if (qg >= NL) continue;
    const f32x16& o0 = half ? oB0 : oA0;
    const f32x16& o1 = half ? oB1 : oA1;
    const float inv = 1.0f / (half ? lB : lA);
    u16* orow = aog + ((size_t)b * NL + qg) * ND + h * NDK;
#pragma unroll
    for (int r = 0; r < 16; r += 2) {
      const int d = (r & 3) + 4 * hi + 8 * (r >> 2);
      *(unsigned*)(orow + d) = cvt_pk_bf16(o0[r] * inv, o0[r + 1] * inv);
      *(unsigned*)(orow + 32 + d) = cvt_pk_bf16(o1[r] * inv, o1[r + 1] * inv);
    }
  }
}

extern "C" void kernel_launch(void* const* d_in, const int* in_sizes, int n_in,
                              void* d_out, int out_size, void* d_ws, size_t ws_size,
                              hipStream_t stream) {
  const float* x      = (const float*)d_in[0];
  const float* gamma1 = (const float*)d_in[1];
  const float* beta1  = (const float*)d_in[2];
  const float* gamma2 = (const float*)d_in[3];
  const float* beta2  = (const float*)d_in[4];
  const float* wq = (const float*)d_in[5];
  const float* bq = (const float*)d_in[6];
  const float* wk = (const float*)d_in[7];
  const float* bk = (const float*)d_in[8];
  const float* wv = (const float*)d_in[9];
  const float* bv = (const float*)d_in[10];
  const float* wo = (const float*)d_in[11];
  const float* bo = (const float*)d_in[12];
  const float* w1 = (const float*)d_in[13];
  const float* b1 = (const float*)d_in[14];
  const float* w2 = (const float*)d_in[15];
  const float* b2 = (const float*)d_in[16];
  float* out = (float*)d_out;

  char* ws = (char*)d_ws;
  size_t off = 0;
  auto take = [&](size_t bytes) { size_t o = off; off += (bytes + 255) & ~(size_t)255; return o; };
  const size_t SLK = 2u << 20;  // tail slack: edge tiles may over-read

  // stats layout: [0..63] = LN1 flat (setup_all atomics; pre-zeroed by memset),
  // [64 .. 64+NBKT*64) = LN2 buckets (gemm_sm<6> bucketed atomics).
  const size_t STATS_B = (64 + NBKT * 64) * 4;
  float* stats = (float*)(ws + take(STATS_B));
  float* stats1 = stats;
  float* stats2 = stats + 64;        // bucket base
  float* cbias = (float*)(ws + take(1536 * 4));
  u16* wqkvT = (u16*)(ws + take((size_t)1536 * 512 * 2));
  u16* woT = (u16*)(ws + take((size_t)512 * 512 * 2));
  u16* w1T = (u16*)(ws + take((size_t)512 * 2048 * 2));
  u16* w2T = (u16*)(ws + take((size_t)2048 * 512 * 2));
  u16* hbuf = (u16*)(ws + take((size_t)NTOK * ND * 2 + SLK));   // h = attn+x, bf16
  u16* qb = (u16*)(ws + take(3 * QKVE * 2 + SLK));
  u16* kb = qb + QKVE;
  u16* vt = kb + QKVE;
  u16* aog = (u16*)(ws + take((size_t)NTOK * ND * 2 + SLK));  // attn out, later ln2 out
  size_t r7 = take((size_t)NTOK * NFF * 2 + SLK);
  u16* xn   = (u16*)(ws + r7);
  u16* ubuf = (u16*)(ws + r7);

  // zero stats FIRST (stream-ordered before any stat atomics)
  hipMemsetAsync(stats, 0, STATS_B, stream);

  // merged setup: concat bias + q/k/v pads + ALL weight transposes + LN1 stats
  setup_all<<<SEG5 / 256, 256, 0, stream>>>(qb, kb, vt, stats, cbias,
                                            bq, bk, bv, wq, wk, wv, wqkvT,
                                            wo, woT, w1, w1T, w2, w2T, x);

  // LN1 apply -> xn (bf16)
  ln_apply<<<2048, 256, 0, stream>>>(x, stats1, gamma1, beta1, xn);

  // merged Q,K,V projection (q scaled by 1/sqrt(512)*log2e for exp2-domain softmax)
  constexpr float QSCALE = 0.04419417382415922f * 1.4426950408889634f;
  gemm_bt<0><<<dim3(145, 12), 256, 0, stream>>>(xn, wqkvT, NTOK, 1536, ND, ND, ND,
                                                cbias, qb, QSCALE);

  // fused flash attention -> aog
  attn_fused<<<dim3(10, NB * NH), 64, 0, stream>>>(qb, kb, vt, aog);

  // output projection + residual(x) -> hbuf (bf16), bucketed LN2 stats
  gemm_sm<6><<<dim3(289, 4), 128, 0, stream>>>(aog, woT, NTOK, ND, ND, ND, ND,
                                               bo, x, ND, hbuf, stats2);

  // LN2 apply -> g (bf16, reuses aog); sums the NBKT buckets in-kernel
  ln_apply_b<<<2048, 256, 0, stream>>>(hbuf, stats2, gamma2, beta2, aog);

  // FFN
  gemm_bt<5><<<dim3(145, 16), 256, 0, stream>>>(aog, w1T, NTOK, NFF, ND, ND, ND,
                                                b1, ubuf, 1.0f);
  gemm_sm<4><<<dim3(289, 4), 128, 0, stream>>>(ubuf, w2T, NTOK, ND, NFF, NFF, NFF,
                                               b2, hbuf, ND, out, nullptr);
}